// Round 2
// baseline (336.026 us; speedup 1.0000x reference)
//
#include <hip/hip_runtime.h>
#include <math.h>

// ExpertGate: scores = sigmoid(X @ W^T); top-8 routing with bias-for-selection,
// gather un-biased scores, renormalize * 2.5. Outputs: weights fp32 (N*8) then
// indices-as-float (N*8), concatenated in d_out.
//
// R2: register-prefetched staging (global latency hidden behind compute),
// BK=128 (half the barriers; 2 blocks/CU is grid-capped so LDS is free),
// launch_bounds(256,2) to give the scheduler VGPR headroom.

#define D_DIM 2048
#define E_DIM 64
#define TOPK 8
#define TM 32          // tokens per block
#define BK 128         // k-chunk
#define XS_STRIDE (BK + 4)   // 132: 16B-aligned rows, 2-way max bank aliasing
#define WS_STRIDE (BK + 4)
#define SC_STRIDE 65

__global__ __launch_bounds__(256, 2) void expert_gate_kernel(
    const float* __restrict__ x,      // (N, 2048)
    const float* __restrict__ w,      // (64, 2048)
    const float* __restrict__ bias,   // (64,)
    float* __restrict__ out,          // N*8 weights, then N*8 indices-as-float
    int N)
{
    __shared__ float Xs[TM * XS_STRIDE];
    __shared__ float Ws[E_DIM * WS_STRIDE];
    __shared__ float Sc[TM * SC_STRIDE];

    const int t    = threadIdx.x;
    const int tx   = t & 15;   // expert group: experts tx + 16*j, j=0..3
    const int ty   = t >> 4;   // token group: tokens ty, ty+16
    const int tok0 = blockIdx.x * TM;
    const int lane = t & 63;

    const float my_bias = bias[lane];

    // staging geometry: 32 lanes cover one row's 128 floats (512 B coalesced)
    const int srow = t >> 5;          // 0..7
    const int scol = (t & 31) << 2;   // 0..124

    const float* xg = &x[(size_t)(tok0 + srow) * D_DIM + scol];
    const float* wg = &w[(size_t)srow * D_DIM + scol];

    float4 xr[4];  // X tile: 32 rows = 4 passes of 8
    float4 wr[8];  // W tile: 64 rows = 8 passes of 8

    // prologue: prefetch chunk 0
    #pragma unroll
    for (int i = 0; i < 4; ++i) xr[i] = *(const float4*)&xg[(size_t)(i * 8) * D_DIM];
    #pragma unroll
    for (int i = 0; i < 8; ++i) wr[i] = *(const float4*)&wg[(size_t)(i * 8) * D_DIM];

    float acc[2][4] = {{0.f,0.f,0.f,0.f},{0.f,0.f,0.f,0.f}};

    for (int k0 = 0; k0 < D_DIM; k0 += BK) {
        // ---- drain staged regs into LDS ----
        #pragma unroll
        for (int i = 0; i < 4; ++i)
            *(float4*)&Xs[(srow + i * 8) * XS_STRIDE + scol] = xr[i];
        #pragma unroll
        for (int i = 0; i < 8; ++i)
            *(float4*)&Ws[(srow + i * 8) * WS_STRIDE + scol] = wr[i];
        __syncthreads();

        // ---- prefetch next chunk while this one computes ----
        const int kn = k0 + BK;
        if (kn < D_DIM) {
            #pragma unroll
            for (int i = 0; i < 4; ++i)
                xr[i] = *(const float4*)&xg[(size_t)(i * 8) * D_DIM + kn];
            #pragma unroll
            for (int i = 0; i < 8; ++i)
                wr[i] = *(const float4*)&wg[(size_t)(i * 8) * D_DIM + kn];
        }

        // ---- compute: 2 tokens x 4 experts per thread ----
        #pragma unroll 4
        for (int kk = 0; kk < BK; kk += 4) {
            float4 a0 = *(const float4*)&Xs[ty * XS_STRIDE + kk];
            float4 a1 = *(const float4*)&Xs[(ty + 16) * XS_STRIDE + kk];
            #pragma unroll
            for (int j = 0; j < 4; ++j) {
                float4 b = *(const float4*)&Ws[(tx + 16 * j) * WS_STRIDE + kk];
                // sequential fp32 accumulation over k (tracks np ref closely)
                acc[0][j] = fmaf(a0.x, b.x, acc[0][j]);
                acc[0][j] = fmaf(a0.y, b.y, acc[0][j]);
                acc[0][j] = fmaf(a0.z, b.z, acc[0][j]);
                acc[0][j] = fmaf(a0.w, b.w, acc[0][j]);
                acc[1][j] = fmaf(a1.x, b.x, acc[1][j]);
                acc[1][j] = fmaf(a1.y, b.y, acc[1][j]);
                acc[1][j] = fmaf(a1.z, b.z, acc[1][j]);
                acc[1][j] = fmaf(a1.w, b.w, acc[1][j]);
            }
        }
        __syncthreads();
    }

    // ---- sigmoid, park scores in LDS ----
    #pragma unroll
    for (int i = 0; i < 2; ++i) {
        #pragma unroll
        for (int j = 0; j < 4; ++j) {
            float s = 1.0f / (1.0f + expf(-acc[i][j]));
            Sc[(ty + 16 * i) * SC_STRIDE + (tx + 16 * j)] = s;
        }
    }
    __syncthreads();

    // ---- top-8 per token: lane == expert; each wave handles 8 tokens ----
    const int wave = t >> 6;  // 0..3
    for (int r = 0; r < 8; ++r) {
        const int tok = wave * 8 + r;
        const float s = Sc[tok * SC_STRIDE + lane];  // original score
        float rv = s + my_bias;                      // routing score
        float outw = 0.f;
        int   outi = 0;
        float ssum = 0.f;
        #pragma unroll
        for (int sel = 0; sel < TOPK; ++sel) {
            float v = rv;
            int   vi = lane;
            // 64-lane butterfly lexicographic max (ties -> lower index)
            #pragma unroll
            for (int off = 1; off < 64; off <<= 1) {
                float ov = __shfl_xor(v, off);
                int   oi = __shfl_xor(vi, off);
                if (ov > v || (ov == v && oi < vi)) { v = ov; vi = oi; }
            }
            float cs = __shfl(s, vi);  // original (un-biased) score of winner
            ssum += cs;
            if (lane == sel) { outw = cs; outi = vi; }
            if (lane == vi) rv = -INFINITY;
        }
        if (lane < TOPK) {
            const size_t base = (size_t)(tok0 + tok) * TOPK + lane;
            out[base] = outw / (ssum + 1e-8f) * 2.5f;
            out[(size_t)N * TOPK + base] = (float)outi;
        }
    }
}

extern "C" void kernel_launch(void* const* d_in, const int* in_sizes, int n_in,
                              void* d_out, int out_size, void* d_ws, size_t ws_size,
                              hipStream_t stream) {
    const float* x    = (const float*)d_in[0];
    const float* w    = (const float*)d_in[1];
    const float* bias = (const float*)d_in[2];
    float* out = (float*)d_out;
    const int N = in_sizes[0] / D_DIM;  // 16384
    const int grid = N / TM;            // 512
    expert_gate_kernel<<<grid, 256, 0, stream>>>(x, w, bias, out, N);
}